// Round 1
// baseline (240.592 us; speedup 1.0000x reference)
//
#include <hip/hip_runtime.h>
#include <hip/hip_bf16.h>
#include <stdint.h>

#define NB 8192
#define NIN 512
#define NH 2048
#define NK (NIN + NH)   // 2560

typedef __bf16 bf16;
typedef __bf16 bf16x4 __attribute__((ext_vector_type(4)));
typedef __bf16 bf16x8 __attribute__((ext_vector_type(8)));
typedef float  f32x4  __attribute__((ext_vector_type(4)));

// ---------------------------------------------------------------------------
// async global->LDS, 16B per lane (wave-uniform LDS base + lane*16)
__device__ __forceinline__ void gload16(const void* g, void* l) {
    __builtin_amdgcn_global_load_lds(
        (const __attribute__((address_space(1))) void*)g,
        (__attribute__((address_space(3))) void*)l,
        16, 0, 0);
}

// ---------------------------------------------------------------------------
// K1: STSP elementwise. Writes syn_x_new, syn_u_new (f32 outputs) and
//     h_post (bf16) into A[row][512+col] of the combined GEMM A matrix.
__global__ void ew_kernel(const float* __restrict__ h_in,
                          const float* __restrict__ syn_x,
                          const float* __restrict__ syn_u,
                          const float* __restrict__ a_stf,
                          const float* __restrict__ a_std,
                          const float* __restrict__ Uv,
                          const float* __restrict__ dyn,
                          float* __restrict__ out_sx,
                          float* __restrict__ out_su,
                          bf16* __restrict__ Abuf)
{
    int t = blockIdx.x * blockDim.x + threadIdx.x;
    int e = t * 4;
    int row = e >> 11;          // / 2048
    int col = e & 2047;
    f32x4 h    = *(const f32x4*)&h_in[e];
    f32x4 sx   = *(const f32x4*)&syn_x[e];
    f32x4 su   = *(const f32x4*)&syn_u[e];
    f32x4 astf = *(const f32x4*)&a_stf[col];
    f32x4 astd = *(const f32x4*)&a_std[col];
    f32x4 Uq   = *(const f32x4*)&Uv[col];
    f32x4 dq   = *(const f32x4*)&dyn[col];
    f32x4 nsx, nsu;
    bf16x4 hpb;
#pragma unroll
    for (int i = 0; i < 4; ++i) {
        float x = sx[i] + (astd[i] * (1.0f - sx[i]) - 0.01f * su[i] * sx[i] * h[i]) * dq[i];
        float u = su[i] + (astf[i] * (Uq[i] - su[i]) + 0.01f * Uq[i] * (1.0f - su[i]) * h[i]) * dq[i];
        x = fminf(fmaxf(x, 0.0f), 1.0f);
        u = fminf(fmaxf(u, 0.0f), 1.0f);
        nsx[i] = x;
        nsu[i] = u;
        hpb[i] = (bf16)(u * x * h[i]);
    }
    *(f32x4*)&out_sx[e] = nsx;
    *(f32x4*)&out_su[e] = nsu;
    *(bf16x4*)&Abuf[(size_t)row * NK + NIN + col] = hpb;
}

// ---------------------------------------------------------------------------
// K2: convert inp (f32, [8192][512]) -> bf16 into A[row][col], col<512
__global__ void conv_inp(const float* __restrict__ inp, bf16* __restrict__ Abuf)
{
    int t = blockIdx.x * blockDim.x + threadIdx.x;
    int e = t * 4;
    int row = e >> 9;           // / 512
    int col = e & 511;
    f32x4 v = *(const f32x4*)&inp[e];
    bf16x4 b;
#pragma unroll
    for (int i = 0; i < 4; ++i) b[i] = (bf16)v[i];
    *(bf16x4*)&Abuf[(size_t)row * NK + col] = b;
}

// ---------------------------------------------------------------------------
// K3: build Bt[N=2048][K=2560] bf16 (transposed effective weights):
//     k <  512: relu(w_ih[k][n])
//     k >= 512: mask[i][n] * EI[i] * relu(w_hh[i][n]),  i = k-512
// LDS-tiled 32x32 transpose so both global read and write are coalesced.
__global__ void prep_w(const float* __restrict__ w_ih,
                       const float* __restrict__ w_hh,
                       const float* __restrict__ w_mask,
                       const float* __restrict__ EI,
                       bf16* __restrict__ Bt)
{
    __shared__ float tile[32][33];
    int b  = blockIdx.x;
    int tk = b % (NK / 32);     // 80 k-tiles
    int tn = b / (NK / 32);     // 64 n-tiles
    int k0 = tk * 32, n0 = tn * 32;
    int t  = threadIdx.x;
    int lc = t & 31;
    int lr = t >> 5;            // 0..7
#pragma unroll
    for (int it = 0; it < 4; ++it) {
        int kr = lr + it * 8;
        int k  = k0 + kr;
        int n  = n0 + lc;
        float v;
        if (k < NIN) {
            v = fmaxf(w_ih[(size_t)k * NH + n], 0.0f);
        } else {
            int i = k - NIN;
            float w = fmaxf(w_hh[(size_t)i * NH + n], 0.0f);
            v = w_mask[(size_t)i * NH + n] * EI[i] * w;
        }
        tile[kr][lc] = v;
    }
    __syncthreads();
#pragma unroll
    for (int it = 0; it < 4; ++it) {
        int nr = lr + it * 8;
        Bt[(size_t)(n0 + nr) * NK + k0 + lc] = (bf16)tile[lc][nr];
    }
}

// ---------------------------------------------------------------------------
// K4: C = A[8192][2560] x Bt[2048][2560]^T, fused epilogue:
//     h_out = 0.9*h_in + 0.1*relu(C + bias)
// m97 structure: 128x128 tile, BK=64, 4 waves (2x2 of 64x64), 16x16x32 MFMA,
// global_load_lds width 16, single LDS buffer, 2 barriers per K-step.
#define BM 128
#define BN 128
#define BK 64

__global__ __launch_bounds__(256)
void gemm_fused(const bf16* __restrict__ A,
                const bf16* __restrict__ Bt,
                const float* __restrict__ h_in,
                const float* __restrict__ bias,
                float* __restrict__ h_out)
{
    __shared__ bf16 As[BM][BK];   // 16 KB
    __shared__ bf16 Bs[BN][BK];   // 16 KB
    int wg = blockIdx.x;
    int tm = wg & 63;             // M/BM = 64  (consecutive wgs share Bt panel)
    int tn = wg >> 6;             // N/BN = 16
    int tid  = threadIdx.x;
    int wid  = tid >> 6;
    int lane = tid & 63;
    int wr = wid >> 1, wc = wid & 1;   // 2x2 waves of 64x64

    f32x4 acc[4][4];
#pragma unroll
    for (int i = 0; i < 4; ++i)
#pragma unroll
        for (int j = 0; j < 4; ++j) acc[i][j] = (f32x4){0.f, 0.f, 0.f, 0.f};

    const int l8  = lane >> 3;        // row within 8-row group
    const int c16 = (lane & 7) * 8;   // bf16 element offset (16B chunks)
    const size_t arow = (size_t)tm * BM;
    const size_t brow = (size_t)tn * BN;
    const int lm = lane & 15;
    const int lk = (lane >> 4) * 8;

    for (int k0 = 0; k0 < NK; k0 += BK) {
#pragma unroll
        for (int c = 0; c < 4; ++c) {
            int r0 = (wid * 4 + c) * 8;   // 8 rows per instruction
            gload16(&A [(arow + r0 + l8) * NK + k0 + c16], &As[r0][0]);
            gload16(&Bt[(brow + r0 + l8) * NK + k0 + c16], &Bs[r0][0]);
        }
        __syncthreads();   // drains vmcnt before use
#pragma unroll
        for (int kk = 0; kk < BK; kk += 32) {
            bf16x8 af[4], bfr[4];
#pragma unroll
            for (int i = 0; i < 4; ++i)
                af[i] = *(const bf16x8*)&As[wr * 64 + i * 16 + lm][kk + lk];
#pragma unroll
            for (int j = 0; j < 4; ++j)
                bfr[j] = *(const bf16x8*)&Bs[wc * 64 + j * 16 + lm][kk + lk];
#pragma unroll
            for (int i = 0; i < 4; ++i)
#pragma unroll
                for (int j = 0; j < 4; ++j)
                    acc[i][j] = __builtin_amdgcn_mfma_f32_16x16x32_bf16(
                        af[i], bfr[j], acc[i][j], 0, 0, 0);
        }
        __syncthreads();
    }

    // epilogue: h_out = 0.9*h_in + 0.1*relu(acc + bias)
    int crow0 = tm * BM + wr * 64 + (lane >> 4) * 4;
    int ccol0 = tn * BN + wc * 64 + lm;
#pragma unroll
    for (int i = 0; i < 4; ++i) {
#pragma unroll
        for (int j = 0; j < 4; ++j) {
            int col = ccol0 + j * 16;
            float bv = bias[col];
#pragma unroll
            for (int r = 0; r < 4; ++r) {
                int row = crow0 + i * 16 + r;
                float pre = acc[i][j][r] + bv;
                float h   = h_in[(size_t)row * NH + col];
                h_out[(size_t)row * NH + col] = 0.9f * h + 0.1f * fmaxf(pre, 0.0f);
            }
        }
    }
}

// ---------------------------------------------------------------------------
extern "C" void kernel_launch(void* const* d_in, const int* in_sizes, int n_in,
                              void* d_out, int out_size, void* d_ws, size_t ws_size,
                              hipStream_t stream)
{
    const float* inp    = (const float*)d_in[0];
    const float* h_in   = (const float*)d_in[1];
    const float* syn_x  = (const float*)d_in[2];
    const float* syn_u  = (const float*)d_in[3];
    const float* w_ih   = (const float*)d_in[4];
    const float* w_hh   = (const float*)d_in[5];
    const float* bias   = (const float*)d_in[6];
    const float* a_stf  = (const float*)d_in[7];
    const float* a_std  = (const float*)d_in[8];
    const float* Uv     = (const float*)d_in[9];
    const float* dyn    = (const float*)d_in[10];
    const float* EI     = (const float*)d_in[11];
    const float* w_mask = (const float*)d_in[12];

    float* out   = (float*)d_out;
    float* out_h = out;                           // h_out
    float* out_x = out + (size_t)NB * NH;         // syn_x_new
    float* out_u = out + 2 * (size_t)NB * NH;     // syn_u_new

    bf16* Abuf = (bf16*)d_ws;                     // [8192][2560] bf16 = 41.9 MB
    bf16* Btw  = Abuf + (size_t)NB * NK;          // [2048][2560] bf16 = 10.5 MB

    // STSP elementwise + h_post->A staging
    ew_kernel<<<(NB * NH) / (256 * 4), 256, 0, stream>>>(
        h_in, syn_x, syn_u, a_stf, a_std, Uv, dyn, out_x, out_u, Abuf);
    // inp -> bf16 into A
    conv_inp<<<(NB * NIN) / (256 * 4), 256, 0, stream>>>(inp, Abuf);
    // effective weights, transposed, bf16
    prep_w<<<(NK / 32) * (NH / 32), 256, 0, stream>>>(w_ih, w_hh, w_mask, EI, Btw);
    // fused GEMM + neuron update
    gemm_fused<<<(NB / BM) * (NH / BN), 256, 0, stream>>>(Abuf, Btw, h_in, bias, out_h);
}

// Round 2
// 190.885 us; speedup vs baseline: 1.2604x; 1.2604x over previous
//
#include <hip/hip_runtime.h>
#include <hip/hip_bf16.h>
#include <stdint.h>

#define NB 8192
#define NIN 512
#define NH 2048
#define NK (NIN + NH)   // 2560
#define NT (NK / 64)    // 40 K-tiles

typedef __bf16 bf16;
typedef __bf16 bf16x4 __attribute__((ext_vector_type(4)));
typedef __bf16 bf16x8 __attribute__((ext_vector_type(8)));
typedef float  f32x4  __attribute__((ext_vector_type(4)));

// ---------------------------------------------------------------------------
__device__ __forceinline__ void gload16(const void* g, void* l) {
    __builtin_amdgcn_global_load_lds(
        (const __attribute__((address_space(1))) void*)g,
        (__attribute__((address_space(3))) void*)l, 16, 0, 0);
}

#define FENCE()      asm volatile("" ::: "memory")
#define BAR()        do { FENCE(); __builtin_amdgcn_s_barrier(); FENCE(); } while (0)
#define WAIT_LGKM0() asm volatile("s_waitcnt lgkmcnt(0)" ::: "memory")
#define WAIT_VM(n)   asm volatile("s_waitcnt vmcnt(" #n ")" ::: "memory")

// ---------------------------------------------------------------------------
// K1: STSP elementwise. Writes syn_x_new, syn_u_new (f32) and h_post (bf16)
//     into A[row][512+col] of the combined GEMM A matrix.
__global__ void ew_kernel(const float* __restrict__ h_in,
                          const float* __restrict__ syn_x,
                          const float* __restrict__ syn_u,
                          const float* __restrict__ a_stf,
                          const float* __restrict__ a_std,
                          const float* __restrict__ Uv,
                          const float* __restrict__ dyn,
                          float* __restrict__ out_sx,
                          float* __restrict__ out_su,
                          bf16* __restrict__ Abuf)
{
    int t = blockIdx.x * blockDim.x + threadIdx.x;
    int e = t * 4;
    int row = e >> 11;
    int col = e & 2047;
    f32x4 h    = *(const f32x4*)&h_in[e];
    f32x4 sx   = *(const f32x4*)&syn_x[e];
    f32x4 su   = *(const f32x4*)&syn_u[e];
    f32x4 astf = *(const f32x4*)&a_stf[col];
    f32x4 astd = *(const f32x4*)&a_std[col];
    f32x4 Uq   = *(const f32x4*)&Uv[col];
    f32x4 dq   = *(const f32x4*)&dyn[col];
    f32x4 nsx, nsu;
    bf16x4 hpb;
#pragma unroll
    for (int i = 0; i < 4; ++i) {
        float x = sx[i] + (astd[i] * (1.0f - sx[i]) - 0.01f * su[i] * sx[i] * h[i]) * dq[i];
        float u = su[i] + (astf[i] * (Uq[i] - su[i]) + 0.01f * Uq[i] * (1.0f - su[i]) * h[i]) * dq[i];
        x = fminf(fmaxf(x, 0.0f), 1.0f);
        u = fminf(fmaxf(u, 0.0f), 1.0f);
        nsx[i] = x;
        nsu[i] = u;
        hpb[i] = (bf16)(u * x * h[i]);
    }
    *(f32x4*)&out_sx[e] = nsx;
    *(f32x4*)&out_su[e] = nsu;
    *(bf16x4*)&Abuf[(size_t)row * NK + NIN + col] = hpb;
}

// ---------------------------------------------------------------------------
// K2: convert inp (f32) -> bf16 into A[row][col], col<512
__global__ void conv_inp(const float* __restrict__ inp, bf16* __restrict__ Abuf)
{
    int t = blockIdx.x * blockDim.x + threadIdx.x;
    int e = t * 4;
    int row = e >> 9;
    int col = e & 511;
    f32x4 v = *(const f32x4*)&inp[e];
    bf16x4 b;
#pragma unroll
    for (int i = 0; i < 4; ++i) b[i] = (bf16)v[i];
    *(bf16x4*)&Abuf[(size_t)row * NK + col] = b;
}

// ---------------------------------------------------------------------------
// K3: build Bt[N=2048][K=2560] bf16 (transposed effective weights).
__global__ void prep_w(const float* __restrict__ w_ih,
                       const float* __restrict__ w_hh,
                       const float* __restrict__ w_mask,
                       const float* __restrict__ EI,
                       bf16* __restrict__ Bt)
{
    __shared__ float tile[32][33];
    int b  = blockIdx.x;
    int tk = b % (NK / 32);
    int tn = b / (NK / 32);
    int k0 = tk * 32, n0 = tn * 32;
    int t  = threadIdx.x;
    int lc = t & 31;
    int lr = t >> 5;
#pragma unroll
    for (int it = 0; it < 4; ++it) {
        int kr = lr + it * 8;
        int k  = k0 + kr;
        int n  = n0 + lc;
        float v;
        if (k < NIN) {
            v = fmaxf(w_ih[(size_t)k * NH + n], 0.0f);
        } else {
            int i = k - NIN;
            float w = fmaxf(w_hh[(size_t)i * NH + n], 0.0f);
            v = w_mask[(size_t)i * NH + n] * EI[i] * w;
        }
        tile[kr][lc] = v;
    }
    __syncthreads();
#pragma unroll
    for (int it = 0; it < 4; ++it) {
        int nr = lr + it * 8;
        Bt[(size_t)(n0 + nr) * NK + k0 + lc] = (bf16)tile[lc][nr];
    }
}

// ---------------------------------------------------------------------------
// K4: 256x256-tile 8-phase GEMM (T1+T2+T3+T4+T5), fused epilogue:
//     h_out = 0.9*h_in + 0.1*relu(C + bias)
//
// LDS layout (per buffer, per matrix, 16K elements = 32KB):
//   A: [u:2][wr:2][r6:64][slot:8][e:8]   logical row r = wr*128 + u*64 + r6
//   B: [u:2][wc:4][n5:32][slot:8][e:8]   logical col n = wc*64  + u*32 + n5
// Swizzle: data for logical slot s of row x stored at LDS slot s ^ (x&7)
// (applied by pre-swizzling the global source col; gload dest stays linear).
//
// Phases per K-tile t (each wave: 128x64 output = 8 Mfrag x 4 Nfrag):
//   P1: MFMA quad (Mhalf0 x Nhalf0)  reads A0+B0 (12 ds_read), stage A1(t+1)
//   P2: MFMA quad (Mhalf0 x Nhalf1)  reads B1 (4),             stage A0(t+2)
//   P3: MFMA quad (Mhalf1 x Nhalf1)  reads A1 (8),             stage B0(t+2)
//   P4: MFMA quad (Mhalf1 x Nhalf0)  reuses regs,              stage B1(t+2)
//       + vmcnt(6) boundary wait (3 half-tiles in flight), never 0 mid-loop.
__global__ __launch_bounds__(512, 2)
void gemm_fused(const bf16* __restrict__ A,
                const bf16* __restrict__ Bt,
                const float* __restrict__ h_in,
                const float* __restrict__ bias,
                float* __restrict__ h_out)
{
    __shared__ bf16 sA[2][16384];   // 64 KB
    __shared__ bf16 sB[2][16384];   // 64 KB

    const int bid  = blockIdx.x;
    const int bid2 = (bid & 7) * 32 + (bid >> 3);   // XCD-aware swizzle (256%8==0)
    const int tm = bid2 >> 3, tn = bid2 & 7;        // tn fast: A-panel L2 reuse
    const int rowBase = tm * 256, colBase = tn * 256;

    const int tid  = threadIdx.x;
    const int wid  = tid >> 6, lane = tid & 63;
    const int wr   = wid >> 2, wc = wid & 3;
    const int ln15 = lane & 15, l4 = lane >> 4;

    // staging: lane covers row (lane>>3), slot (lane&7); source col pre-swizzled
    const int sr  = lane >> 3;
    const int gcs = (((lane & 7) ^ sr) << 3);   // global element col within K-tile
    // ds_read: swizzled slot offsets in elements (kk=0 / kk=1)
    const int sk0 = ((l4 ^ (ln15 & 7)) << 3);
    const int sk1 = sk0 ^ 32;

    f32x4 acc[8][4];
#pragma unroll
    for (int i = 0; i < 8; ++i)
#pragma unroll
        for (int j = 0; j < 4; ++j) acc[i][j] = (f32x4){0.f, 0.f, 0.f, 0.f};

    bf16x8 af[4][2], bf0[2][2], bf1[2][2];

    auto stA = [&](bf16* dst, int T, int u) {
#pragma unroll
        for (int w = 0; w < 2; ++w) {
            int gr = rowBase + w * 128 + u * 64 + wid * 8 + sr;
            gload16(A + (size_t)gr * NK + T * 64 + gcs,
                    dst + u * 8192 + w * 4096 + wid * 512);
        }
    };
    auto stB = [&](bf16* dst, int T, int u) {
#pragma unroll
        for (int w = 0; w < 2; ++w) {
            int gn = colBase + (w * 2 + (wid >> 2)) * 64 + u * 32 + (wid & 3) * 8 + sr;
            gload16(Bt + (size_t)gn * NK + T * 64 + gcs,
                    dst + u * 8192 + w * 4096 + wid * 512);
        }
    };

#define READ_A(MH) do {                                                        \
    const bf16* _ba = &sAc[(MH) * 8192 + wr * 4096 + ln15 * 64];               \
    _Pragma("unroll") for (int m = 0; m < 4; ++m) {                            \
        af[m][0] = *(const bf16x8*)(_ba + m * 1024 + sk0);                     \
        af[m][1] = *(const bf16x8*)(_ba + m * 1024 + sk1); } } while (0)

#define READ_B(NHALF, bfr) do {                                                \
    const bf16* _bb = &sBc[(NHALF) * 8192 + wc * 2048 + ln15 * 64];            \
    _Pragma("unroll") for (int n = 0; n < 2; ++n) {                            \
        bfr[n][0] = *(const bf16x8*)(_bb + n * 1024 + sk0);                    \
        bfr[n][1] = *(const bf16x8*)(_bb + n * 1024 + sk1); } } while (0)

#define MFMA16(MH, NHALF, bfr) do {                                            \
    __builtin_amdgcn_s_setprio(1);                                             \
    _Pragma("unroll") for (int m = 0; m < 4; ++m)                              \
    _Pragma("unroll") for (int n = 0; n < 2; ++n)                              \
    _Pragma("unroll") for (int kk = 0; kk < 2; ++kk)                           \
        acc[(MH) * 4 + m][(NHALF) * 2 + n] =                                   \
            __builtin_amdgcn_mfma_f32_16x16x32_bf16(                           \
                af[m][kk], bfr[n][kk], acc[(MH) * 4 + m][(NHALF) * 2 + n],     \
                0, 0, 0);                                                      \
    __builtin_amdgcn_s_setprio(0); } while (0)

#define TILE(t, sAc_, sBc_, sAn_, sBn_) do {                                   \
    const bf16* sAc = sAc_; const bf16* sBc = sBc_;                            \
    /* P1 */                                                                   \
    READ_A(0); READ_B(0, bf0);                                                 \
    if ((t) + 1 < NT) stA(sAn_, (t) + 1, 1);                                   \
    BAR(); WAIT_LGKM0(); MFMA16(0, 0, bf0); BAR();                             \
    /* P2 */                                                                   \
    READ_B(1, bf1);                                                            \
    if ((t) + 2 < NT) stA((bf16*)sAc_, (t) + 2, 0);                            \
    BAR(); WAIT_LGKM0(); MFMA16(0, 1, bf1); BAR();                             \
    /* P3 */                                                                   \
    READ_A(1);                                                                 \
    if ((t) + 2 < NT) stB((bf16*)sBc_, (t) + 2, 0);                            \
    BAR(); WAIT_LGKM0(); MFMA16(1, 1, bf1); BAR();                             \
    /* P4 */                                                                   \
    if ((t) + 2 < NT) stB((bf16*)sBc_, (t) + 2, 1);                            \
    BAR(); WAIT_LGKM0(); MFMA16(1, 0, bf0);                                    \
    if ((t) + 2 < NT) { WAIT_VM(6); }                                          \
    else if ((t) + 1 < NT) { WAIT_VM(0); }                                     \
    BAR(); } while (0)

    // prologue: tile0 {A0,B0,A1,B1}, tile1 {A0,B0,B1}; A1(1) staged in P1 of t0
    stA(sA[0], 0, 0); stB(sB[0], 0, 0); stA(sA[0], 0, 1); stB(sB[0], 0, 1);
    stA(sA[1], 1, 0); stB(sB[1], 1, 0); stB(sB[1], 1, 1);
    WAIT_VM(6);   // tile0 resident; 3 half-tiles of tile1 in flight
    BAR();

    for (int t = 0; t < NT; t += 2) {
        TILE(t,     sA[0], sB[0], sA[1], sB[1]);
        TILE(t + 1, sA[1], sB[1], sA[0], sB[0]);
    }

    // epilogue: h_out = 0.9*h_in + 0.1*relu(acc + bias)
#pragma unroll
    for (int mf = 0; mf < 8; ++mf) {
#pragma unroll
        for (int nf = 0; nf < 4; ++nf) {
            int col = colBase + wc * 64 + nf * 16 + ln15;
            float bv = bias[col];
            int row0 = rowBase + wr * 128 + mf * 16 + l4 * 4;
#pragma unroll
            for (int r = 0; r < 4; ++r) {
                size_t idx = (size_t)(row0 + r) * NH + col;
                float pre = acc[mf][nf][r] + bv;
                h_out[idx] = 0.9f * h_in[idx] + 0.1f * fmaxf(pre, 0.0f);
            }
        }
    }
#undef READ_A
#undef READ_B
#undef MFMA16
#undef TILE
}

// ---------------------------------------------------------------------------
extern "C" void kernel_launch(void* const* d_in, const int* in_sizes, int n_in,
                              void* d_out, int out_size, void* d_ws, size_t ws_size,
                              hipStream_t stream)
{
    const float* inp    = (const float*)d_in[0];
    const float* h_in   = (const float*)d_in[1];
    const float* syn_x  = (const float*)d_in[2];
    const float* syn_u  = (const float*)d_in[3];
    const float* w_ih   = (const float*)d_in[4];
    const float* w_hh   = (const float*)d_in[5];
    const float* bias   = (const float*)d_in[6];
    const float* a_stf  = (const float*)d_in[7];
    const float* a_std  = (const float*)d_in[8];
    const float* Uv     = (const float*)d_in[9];
    const float* dyn    = (const float*)d_in[10];
    const float* EI     = (const float*)d_in[11];
    const float* w_mask = (const float*)d_in[12];

    float* out   = (float*)d_out;
    float* out_h = out;
    float* out_x = out + (size_t)NB * NH;
    float* out_u = out + 2 * (size_t)NB * NH;

    bf16* Abuf = (bf16*)d_ws;                     // [8192][2560] bf16
    bf16* Btw  = Abuf + (size_t)NB * NK;          // [2048][2560] bf16

    ew_kernel<<<(NB * NH) / (256 * 4), 256, 0, stream>>>(
        h_in, syn_x, syn_u, a_stf, a_std, Uv, dyn, out_x, out_u, Abuf);
    conv_inp<<<(NB * NIN) / (256 * 4), 256, 0, stream>>>(inp, Abuf);
    prep_w<<<(NK / 32) * (NH / 32), 256, 0, stream>>>(w_ih, w_hh, w_mask, EI, Btw);
    gemm_fused<<<(NB / 256) * (NH / 256), 512, 0, stream>>>(Abuf, Btw, h_in, bias, out_h);
}

// Round 3
// 184.066 us; speedup vs baseline: 1.3071x; 1.0370x over previous
//
#include <hip/hip_runtime.h>
#include <hip/hip_bf16.h>
#include <stdint.h>

#define NB 8192
#define NIN 512
#define NH 2048
#define NK (NIN + NH)   // 2560
#define NT (NK / 64)    // 40 K-tiles

typedef __bf16 bf16;
typedef __bf16 bf16x4 __attribute__((ext_vector_type(4)));
typedef __bf16 bf16x8 __attribute__((ext_vector_type(8)));
typedef float  f32x4  __attribute__((ext_vector_type(4)));

// ---------------------------------------------------------------------------
__device__ __forceinline__ void gload16(const void* g, void* l) {
    __builtin_amdgcn_global_load_lds(
        (const __attribute__((address_space(1))) void*)g,
        (__attribute__((address_space(3))) void*)l, 16, 0, 0);
}

#define FENCE()      asm volatile("" ::: "memory")
#define BAR()        do { FENCE(); __builtin_amdgcn_s_barrier(); FENCE(); } while (0)
#define WAIT_LGKM0() asm volatile("s_waitcnt lgkmcnt(0)" ::: "memory")
#define WAIT_LGKM8() asm volatile("s_waitcnt lgkmcnt(8)" ::: "memory")
#define WAIT_VM(n)   asm volatile("s_waitcnt vmcnt(" #n ")" ::: "memory")

// ---------------------------------------------------------------------------
// K1: STSP elementwise. Writes syn_x_new, syn_u_new (f32) and h_post (bf16)
//     into A[row][512+col] of the combined GEMM A matrix.
__global__ void ew_kernel(const float* __restrict__ h_in,
                          const float* __restrict__ syn_x,
                          const float* __restrict__ syn_u,
                          const float* __restrict__ a_stf,
                          const float* __restrict__ a_std,
                          const float* __restrict__ Uv,
                          const float* __restrict__ dyn,
                          float* __restrict__ out_sx,
                          float* __restrict__ out_su,
                          bf16* __restrict__ Abuf)
{
    int t = blockIdx.x * blockDim.x + threadIdx.x;
    int e = t * 4;
    int row = e >> 11;
    int col = e & 2047;
    f32x4 h    = *(const f32x4*)&h_in[e];
    f32x4 sx   = *(const f32x4*)&syn_x[e];
    f32x4 su   = *(const f32x4*)&syn_u[e];
    f32x4 astf = *(const f32x4*)&a_stf[col];
    f32x4 astd = *(const f32x4*)&a_std[col];
    f32x4 Uq   = *(const f32x4*)&Uv[col];
    f32x4 dq   = *(const f32x4*)&dyn[col];
    f32x4 nsx, nsu;
    bf16x4 hpb;
#pragma unroll
    for (int i = 0; i < 4; ++i) {
        float x = sx[i] + (astd[i] * (1.0f - sx[i]) - 0.01f * su[i] * sx[i] * h[i]) * dq[i];
        float u = su[i] + (astf[i] * (Uq[i] - su[i]) + 0.01f * Uq[i] * (1.0f - su[i]) * h[i]) * dq[i];
        x = fminf(fmaxf(x, 0.0f), 1.0f);
        u = fminf(fmaxf(u, 0.0f), 1.0f);
        nsx[i] = x;
        nsu[i] = u;
        hpb[i] = (bf16)(u * x * h[i]);
    }
    *(f32x4*)&out_sx[e] = nsx;
    *(f32x4*)&out_su[e] = nsu;
    *(bf16x4*)&Abuf[(size_t)row * NK + NIN + col] = hpb;
}

// ---------------------------------------------------------------------------
// K2: convert inp (f32) -> bf16 into A[row][col], col<512
__global__ void conv_inp(const float* __restrict__ inp, bf16* __restrict__ Abuf)
{
    int t = blockIdx.x * blockDim.x + threadIdx.x;
    int e = t * 4;
    int row = e >> 9;
    int col = e & 511;
    f32x4 v = *(const f32x4*)&inp[e];
    bf16x4 b;
#pragma unroll
    for (int i = 0; i < 4; ++i) b[i] = (bf16)v[i];
    *(bf16x4*)&Abuf[(size_t)row * NK + col] = b;
}

// ---------------------------------------------------------------------------
// K3: build Bt[N=2048][K=2560] bf16 (transposed effective weights).
__global__ void prep_w(const float* __restrict__ w_ih,
                       const float* __restrict__ w_hh,
                       const float* __restrict__ w_mask,
                       const float* __restrict__ EI,
                       bf16* __restrict__ Bt)
{
    __shared__ float tile[32][33];
    int b  = blockIdx.x;
    int tk = b % (NK / 32);
    int tn = b / (NK / 32);
    int k0 = tk * 32, n0 = tn * 32;
    int t  = threadIdx.x;
    int lc = t & 31;
    int lr = t >> 5;
#pragma unroll
    for (int it = 0; it < 4; ++it) {
        int kr = lr + it * 8;
        int k  = k0 + kr;
        int n  = n0 + lc;
        float v;
        if (k < NIN) {
            v = fmaxf(w_ih[(size_t)k * NH + n], 0.0f);
        } else {
            int i = k - NIN;
            float w = fmaxf(w_hh[(size_t)i * NH + n], 0.0f);
            v = w_mask[(size_t)i * NH + n] * EI[i] * w;
        }
        tile[kr][lc] = v;
    }
    __syncthreads();
#pragma unroll
    for (int it = 0; it < 4; ++it) {
        int nr = lr + it * 8;
        Bt[(size_t)(n0 + nr) * NK + k0 + lc] = (bf16)tile[lc][nr];
    }
}

// ---------------------------------------------------------------------------
// K4: 256x256-tile 8-phase GEMM (T1+T2+T3+T4+T5), fused epilogue:
//     h_out = 0.9*h_in + 0.1*relu(C + bias)
// Changes vs R1: kk-outer MFMA order (no back-to-back dependent MFMAs),
// branch-free steady K-loop (tail peeled), lgkmcnt(8) pacing in the 12-read
// phase, P4 opening barrier + lgkm wait removed (operands reg-resident;
// restage hazard ordered by P3's closing barrier).
__global__ __launch_bounds__(512, 2)
void gemm_fused(const bf16* __restrict__ A,
                const bf16* __restrict__ Bt,
                const float* __restrict__ h_in,
                const float* __restrict__ bias,
                float* __restrict__ h_out)
{
    __shared__ bf16 sA[2][16384];   // 64 KB
    __shared__ bf16 sB[2][16384];   // 64 KB

    const int bid  = blockIdx.x;
    const int bid2 = (bid & 7) * 32 + (bid >> 3);   // XCD-aware swizzle (256%8==0)
    const int tm = bid2 >> 3, tn = bid2 & 7;
    const int rowBase = tm * 256, colBase = tn * 256;

    const int tid  = threadIdx.x;
    const int wid  = tid >> 6, lane = tid & 63;
    const int wr   = wid >> 2, wc = wid & 3;
    const int ln15 = lane & 15, l4 = lane >> 4;

    // staging: lane covers row (lane>>3), slot (lane&7); source col pre-swizzled
    const int sr  = lane >> 3;
    const int gcs = (((lane & 7) ^ sr) << 3);
    // ds_read: swizzled slot offsets in elements (kk=0 / kk=1)
    const int sk0 = ((l4 ^ (ln15 & 7)) << 3);
    const int sk1 = sk0 ^ 32;

    f32x4 acc[8][4];
#pragma unroll
    for (int i = 0; i < 8; ++i)
#pragma unroll
        for (int j = 0; j < 4; ++j) acc[i][j] = (f32x4){0.f, 0.f, 0.f, 0.f};

    bf16x8 af[4][2], bf0[2][2], bf1[2][2];

    auto stA = [&](bf16* dst, int T, int u) {
#pragma unroll
        for (int w = 0; w < 2; ++w) {
            int gr = rowBase + w * 128 + u * 64 + wid * 8 + sr;
            gload16(A + (size_t)gr * NK + T * 64 + gcs,
                    dst + u * 8192 + w * 4096 + wid * 512);
        }
    };
    auto stB = [&](bf16* dst, int T, int u) {
#pragma unroll
        for (int w = 0; w < 2; ++w) {
            int gn = colBase + (w * 2 + (wid >> 2)) * 64 + u * 32 + (wid & 3) * 8 + sr;
            gload16(Bt + (size_t)gn * NK + T * 64 + gcs,
                    dst + u * 8192 + w * 4096 + wid * 512);
        }
    };

#define READ_A(MH) do {                                                        \
    const bf16* _ba = &sAc[(MH) * 8192 + wr * 4096 + ln15 * 64];               \
    _Pragma("unroll") for (int m = 0; m < 4; ++m) {                            \
        af[m][0] = *(const bf16x8*)(_ba + m * 1024 + sk0);                     \
        af[m][1] = *(const bf16x8*)(_ba + m * 1024 + sk1); } } while (0)

#define READ_B(NHALF, bfr) do {                                                \
    const bf16* _bb = &sBc[(NHALF) * 8192 + wc * 2048 + ln15 * 64];            \
    _Pragma("unroll") for (int n = 0; n < 2; ++n) {                            \
        bfr[n][0] = *(const bf16x8*)(_bb + n * 1024 + sk0);                    \
        bfr[n][1] = *(const bf16x8*)(_bb + n * 1024 + sk1); } } while (0)

// kk OUTER: 8 independent MFMAs between the two dependent writes to each acc
#define MFMA16(MH, NHALF, bfr) do {                                            \
    __builtin_amdgcn_s_setprio(1);                                             \
    _Pragma("unroll") for (int kk = 0; kk < 2; ++kk)                           \
    _Pragma("unroll") for (int m = 0; m < 4; ++m)                              \
    _Pragma("unroll") for (int n = 0; n < 2; ++n)                              \
        acc[(MH) * 4 + m][(NHALF) * 2 + n] =                                   \
            __builtin_amdgcn_mfma_f32_16x16x32_bf16(                           \
                af[m][kk], bfr[n][kk], acc[(MH) * 4 + m][(NHALF) * 2 + n],     \
                0, 0, 0);                                                      \
    __builtin_amdgcn_s_setprio(0); } while (0)

// S1/S2 are literal 0/1 (constant-folded). VMW is the end-of-tile wait stmt.
#define TILE(t, sAc_, sBc_, sAn_, sBn_, S1, S2, VMW) do {                      \
    const bf16* sAc = sAc_; const bf16* sBc = sBc_;                            \
    /* P1 */                                                                   \
    READ_A(0); READ_B(0, bf0);                                                 \
    if (S1) stA(sAn_, (t) + 1, 1);                                             \
    WAIT_LGKM8();                                                              \
    BAR(); WAIT_LGKM0(); MFMA16(0, 0, bf0); BAR();                             \
    /* P2 */                                                                   \
    READ_B(1, bf1);                                                            \
    if (S2) stA((bf16*)sAc_, (t) + 2, 0);                                      \
    BAR(); WAIT_LGKM0(); MFMA16(0, 1, bf1); BAR();                             \
    /* P3 */                                                                   \
    READ_A(1);                                                                 \
    if (S2) stB((bf16*)sBc_, (t) + 2, 0);                                      \
    BAR(); WAIT_LGKM0(); MFMA16(1, 1, bf1); BAR();                             \
    /* P4: operands reg-resident; no opening barrier needed */                 \
    if (S2) stB((bf16*)sBc_, (t) + 2, 1);                                      \
    MFMA16(1, 0, bf0);                                                         \
    VMW;                                                                       \
    BAR(); } while (0)

    // prologue: tile0 {A0,B0,A1,B1}, tile1 {A0,B0,B1}; A1(1) staged in P1 of t0
    stA(sA[0], 0, 0); stB(sB[0], 0, 0); stA(sA[0], 0, 1); stB(sB[0], 0, 1);
    stA(sA[1], 1, 0); stB(sB[1], 1, 0); stB(sB[1], 1, 1);
    WAIT_VM(6);   // tile0 resident; 3 half-tiles of tile1 in flight
    BAR();

    // steady state: tiles 0..NT-3 fully unconditional (stages reach NT-1 max)
    for (int t = 0; t < NT - 2; t += 2) {
        TILE(t,     sA[0], sB[0], sA[1], sB[1], 1, 1, WAIT_VM(6));
        TILE(t + 1, sA[1], sB[1], sA[0], sB[0], 1, 1, WAIT_VM(6));
    }
    // tail: tile NT-2 stages only A1(NT-1), then drains; tile NT-1 stages nothing
    TILE(NT - 2, sA[0], sB[0], sA[1], sB[1], 1, 0, WAIT_VM(0));
    TILE(NT - 1, sA[1], sB[1], sA[0], sB[0], 0, 0, FENCE());

    // epilogue: h_out = 0.9*h_in + 0.1*relu(acc + bias)
#pragma unroll
    for (int mf = 0; mf < 8; ++mf) {
#pragma unroll
        for (int nf = 0; nf < 4; ++nf) {
            int col = colBase + wc * 64 + nf * 16 + ln15;
            float bv = bias[col];
            int row0 = rowBase + wr * 128 + mf * 16 + l4 * 4;
#pragma unroll
            for (int r = 0; r < 4; ++r) {
                size_t idx = (size_t)(row0 + r) * NH + col;
                float pre = acc[mf][nf][r] + bv;
                h_out[idx] = 0.9f * h_in[idx] + 0.1f * fmaxf(pre, 0.0f);
            }
        }
    }
#undef READ_A
#undef READ_B
#undef MFMA16
#undef TILE
}

// ---------------------------------------------------------------------------
extern "C" void kernel_launch(void* const* d_in, const int* in_sizes, int n_in,
                              void* d_out, int out_size, void* d_ws, size_t ws_size,
                              hipStream_t stream)
{
    const float* inp    = (const float*)d_in[0];
    const float* h_in   = (const float*)d_in[1];
    const float* syn_x  = (const float*)d_in[2];
    const float* syn_u  = (const float*)d_in[3];
    const float* w_ih   = (const float*)d_in[4];
    const float* w_hh   = (const float*)d_in[5];
    const float* bias   = (const float*)d_in[6];
    const float* a_stf  = (const float*)d_in[7];
    const float* a_std  = (const float*)d_in[8];
    const float* Uv     = (const float*)d_in[9];
    const float* dyn    = (const float*)d_in[10];
    const float* EI     = (const float*)d_in[11];
    const float* w_mask = (const float*)d_in[12];

    float* out   = (float*)d_out;
    float* out_h = out;
    float* out_x = out + (size_t)NB * NH;
    float* out_u = out + 2 * (size_t)NB * NH;

    bf16* Abuf = (bf16*)d_ws;                     // [8192][2560] bf16
    bf16* Btw  = Abuf + (size_t)NB * NK;          // [2048][2560] bf16

    ew_kernel<<<(NB * NH) / (256 * 4), 256, 0, stream>>>(
        h_in, syn_x, syn_u, a_stf, a_std, Uv, dyn, out_x, out_u, Abuf);
    conv_inp<<<(NB * NIN) / (256 * 4), 256, 0, stream>>>(inp, Abuf);
    prep_w<<<(NK / 32) * (NH / 32), 256, 0, stream>>>(w_ih, w_hh, w_mask, EI, Btw);
    gemm_fused<<<(NB / 256) * (NH / 256), 512, 0, stream>>>(Abuf, Btw, h_in, bias, out_h);
}